// Round 10
// baseline (275.549 us; speedup 1.0000x reference)
//
#include <hip/hip_runtime.h>
#include <hip/hip_bf16.h>

// Problem constants (static per reference setup_inputs)
#define NB    2
#define LQ    13294
#define DM    256
#define NH    8
#define HD    32
#define NL    4
#define NP    4
#define ROWS  (NB*LQ)   // 26588 = 4 * 6647 exactly

// ws byte offsets (all 16B-aligned)
#define OFF_VALUE 0u            // bf16 [ROWS][256]
#define OFF_TMP   13613056u     // bf16 [ROWS][256]
#define OFF_OFFS  27226112u     // f32  [ROWS][256]
#define OFF_AWL   54452224u     // bf16 [ROWS][128]
#define OFF_WT    61258752u     // bf16: WvT[256][256], WoffT[256][256], WattnT[128][256], WoutT[256][256]
#define OFF_FLAG  61717504u     // int

#define WT_WV    0
#define WT_WOFF  65536
#define WT_WATTN 131072        // == WT_WOFF + 256*256 (contiguous -> fused N=384 GEMM)
#define WT_WOUT  163840

#define NPANEL   831           // ceil(ROWS/32); last panel has 28 valid rows
#define NGRID_IN (NPANEL*2)    // 1662: b<831 value panel, else fused panel
#define NGRID_OUT NPANEL

typedef __attribute__((ext_vector_type(8))) short short8;
typedef __attribute__((ext_vector_type(4))) float floatx4;

static __device__ __forceinline__ float blo(int u)  { return __uint_as_float(((unsigned)u) << 16); }
static __device__ __forceinline__ float bhif(int u) { return __uint_as_float(((unsigned)u) & 0xffff0000u); }

static __device__ __forceinline__ int pack_bf2(float a, float b) {
    __hip_bfloat162 h(__float2bfloat16(a), __float2bfloat16(b));
    int u; __builtin_memcpy(&u, &h, 4); return u;
}

// XCD-chunked bijective block->chunk remap (guide T1 + m204 form).
static __device__ __forceinline__ int xcd_swz(int b, int nblk) {
    const int q = nblk >> 3, r = nblk & 7;
    const int x = b & 7, i = b >> 3;
    return x * q + min(x, r) + i;
}

// ---------------------------------------------------------------------------
// dtype sniffer (flag: 1 = buffers bf16-packed, 0 = f32)
__global__ void sniff_k(const unsigned int* __restrict__ q, int* __restrict__ flag) {
    const int t = threadIdx.x;  // 64
    int hits = 0;
#pragma unroll
    for (int i = 0; i < 4; ++i) {
        unsigned lo = q[t * 4 + i] & 0xffffu;
        unsigned e  = (lo >> 7) & 0xffu;
        if ((e >= 110u && e <= 132u) || lo == 0u) ++hits;
    }
#pragma unroll
    for (int s = 1; s < 64; s <<= 1) hits += __shfl_xor(hits, s);
    if (t == 0) *flag = (hits > 160) ? 1 : 0;
}

// ---------------------------------------------------------------------------
// Transpose W[K=256][N] -> Wt[N][256] bf16 (converting from f32 if flag==0).
__global__ __launch_bounds__(256) void trans_k(
    const void* __restrict__ s0, const void* __restrict__ s1,
    const void* __restrict__ s2, const void* __restrict__ s3,
    short* __restrict__ wt, const int* __restrict__ flagp)
{
    const int flag = *flagp;
    const int z = blockIdx.z;
    const void* src = (z == 0) ? s0 : (z == 1) ? s1 : (z == 2) ? s2 : s3;
    short* dst = wt + ((z == 0) ? WT_WV : (z == 1) ? WT_WOFF : (z == 2) ? WT_WATTN : WT_WOUT);
    const int N = (z == 2) ? 128 : 256;
    const int n0 = blockIdx.x * 32, k0 = blockIdx.y * 32;
    if (n0 >= N) return;

    __shared__ short tile[32 * 36];
    const int t = threadIdx.x;
    const int r = t >> 3, c4 = (t & 7) * 4;
    if (flag) {
        const short* sp = (const short*)src + (k0 + r) * N + n0 + c4;
        *(short4*)&tile[r * 36 + c4] = *(const short4*)sp;
    } else {
        const float* sp = (const float*)src + (k0 + r) * N + n0 + c4;
        float4 v = *(const float4*)sp;
        short4 o;
        o.x = (short)(pack_bf2(v.x, v.x) & 0xffff);
        o.y = (short)(pack_bf2(v.y, v.y) & 0xffff);
        o.z = (short)(pack_bf2(v.z, v.z) & 0xffff);
        o.w = (short)(pack_bf2(v.w, v.w) & 0xffff);
        *(short4*)&tile[r * 36 + c4] = o;
    }
    __syncthreads();
    const int nn = t >> 3, r4 = (t & 7) * 4;
    short4 o;
    o.x = tile[(r4 + 0) * 36 + nn];
    o.y = tile[(r4 + 1) * 36 + nn];
    o.z = tile[(r4 + 2) * 36 + nn];
    o.w = tile[(r4 + 3) * 36 + nn];
    *(short4*)&dst[(n0 + nn) * 256 + k0 + r4] = o;
}

// ---------------------------------------------------------------------------
// Wave-GEMM compute (unchanged from R6-R9): one wave per 32(row) x NJ*16(col)
// tile, no LDS in the K-loop, no barriers. R10 changes ONLY the writeback:
// R9 post-mortem showed dur pinned at ~0.9 TB/s with all pipes idle across
// traffic/locality/TLP fixes -> limiter is HBM efficiency of the scattered
// 32-64B C-store segments (R5's WRITE_SIZE showed 2x amplification = partial
// 128B-line RMW). Fix: stage C in LDS, one barrier, cooperative full-row
// linear copy (consecutive threads -> consecutive int4 -> full 512B/1KB rows).
static __device__ __forceinline__ short8 ldA_f32(const float* p) {
    float4 f0 = *(const float4*)p, f1 = *(const float4*)(p + 4);
    int4 q; q.x = pack_bf2(f0.x, f0.y); q.y = pack_bf2(f0.z, f0.w);
            q.z = pack_bf2(f1.x, f1.y); q.w = pack_bf2(f1.z, f1.w);
    short8 r; __builtin_memcpy(&r, &q, 16); return r;
}

template<int NJ>
static __device__ __forceinline__ void wg_compute(
    const void* __restrict__ A, const short* __restrict__ Wt,
    const bool a_bf, const int bm, const int bn, const int lane,
    floatx4 (&acc)[2][NJ])
{
    const int qd = lane >> 4, ln = lane & 15;
    const int ar0 = min(bm + ln, ROWS - 1);       // clamp OOB rows (loads only)
    const int ar1 = min(bm + 16 + ln, ROWS - 1);
    const short* Ab = (const short*)A;
    const float* Af = (const float*)A;

#pragma unroll
    for (int i = 0; i < 2; ++i)
#pragma unroll
        for (int j = 0; j < NJ; ++j) acc[i][j] = floatx4{0.f, 0.f, 0.f, 0.f};

    if (a_bf) {
#pragma unroll 2
        for (int kk = 0; kk < 8; ++kk) {
            const int k0 = kk * 32 + qd * 8;
            short8 af0 = *(const short8*)(Ab + ar0 * 256 + k0);
            short8 af1 = *(const short8*)(Ab + ar1 * 256 + k0);
            short8 bf[NJ];
#pragma unroll
            for (int j = 0; j < NJ; ++j)
                bf[j] = *(const short8*)(Wt + (bn + j * 16 + ln) * 256 + k0);
#pragma unroll
            for (int j = 0; j < NJ; ++j) {
                acc[0][j] = __builtin_amdgcn_mfma_f32_16x16x32_bf16(af0, bf[j], acc[0][j], 0, 0, 0);
                acc[1][j] = __builtin_amdgcn_mfma_f32_16x16x32_bf16(af1, bf[j], acc[1][j], 0, 0, 0);
            }
        }
    } else {
#pragma unroll 2
        for (int kk = 0; kk < 8; ++kk) {
            const int k0 = kk * 32 + qd * 8;
            short8 af0 = ldA_f32(Af + ar0 * 256 + k0);
            short8 af1 = ldA_f32(Af + ar1 * 256 + k0);
            short8 bf[NJ];
#pragma unroll
            for (int j = 0; j < NJ; ++j)
                bf[j] = *(const short8*)(Wt + (bn + j * 16 + ln) * 256 + k0);
#pragma unroll
            for (int j = 0; j < NJ; ++j) {
                acc[0][j] = __builtin_amdgcn_mfma_f32_16x16x32_bf16(af0, bf[j], acc[0][j], 0, 0, 0);
                acc[1][j] = __builtin_amdgcn_mfma_f32_16x16x32_bf16(af1, bf[j], acc[1][j], 0, 0, 0);
            }
        }
    }
}

// merged input GEMMs: block (256 thr = 4 waves) owns a 32-row panel x full N.
// b<831: value (N=256, wave -> 64 cols); else fused (N=384, wave -> 96 cols).
__global__ __launch_bounds__(256) void wgemm_in_k(
    const void* __restrict__ flat, const void* __restrict__ query,
    const short* __restrict__ wt,
    const void* __restrict__ bv, const void* __restrict__ boff,
    const void* __restrict__ battn,
    void* __restrict__ value, void* __restrict__ offsb, void* __restrict__ awl,
    const int* __restrict__ flagp)
{
    __shared__ __align__(16) char smem[40960];   // value: 16KB bf16 C | fused: 32KB f32 offs + 8KB bf16 awl
    const int flag = *flagp;
    const bool a_bf = (flag != 0);
    const int b = xcd_swz(blockIdx.x, NGRID_IN);
    const int tid = threadIdx.x, wv = tid >> 6, lane = tid & 63;
    const int qd = lane >> 4, ln = lane & 15;

    if (b < NPANEL) {
        const int p = b, bm = p * 32;
        floatx4 acc[2][4];
        wg_compute<4>(flat, wt + WT_WV, a_bf, bm, wv * 64, lane, acc);

        short* Cs = (short*)smem;
#pragma unroll
        for (int j = 0; j < 4; ++j) {
            const int col = wv * 64 + j * 16 + ln;
            const float bj = flag ? __bfloat162float(((const __hip_bfloat16*)bv)[col])
                                  : ((const float*)bv)[col];
#pragma unroll
            for (int i = 0; i < 2; ++i)
#pragma unroll
                for (int r = 0; r < 4; ++r)
                    Cs[(i * 16 + qd * 4 + r) * 256 + col] =
                        (short)(pack_bf2(acc[i][j][r] + bj, 0.f) & 0xffff);
        }
        __syncthreads();
        const int rows_valid = min(32, ROWS - bm);
        const int4* src = (const int4*)smem;
        int4* dst = (int4*)((char*)value + (size_t)p * 16384);
#pragma unroll
        for (int c = 0; c < 4; ++c) {
            const int idx = c * 256 + tid;
            if (idx < rows_valid * 32) dst[idx] = src[idx];
        }
    } else {
        const int p = b - NPANEL, bm = p * 32;
        floatx4 acc[2][6];
        wg_compute<6>(query, wt + WT_WOFF, a_bf, bm, wv * 96, lane, acc);

        float* Os = (float*)smem;            // [32][256] f32
        short* Al = (short*)(smem + 32768);  // [32][128] bf16
#pragma unroll
        for (int j = 0; j < 6; ++j) {
            const int col = wv * 96 + j * 16 + ln;
            float bj;
            if (col < 256) bj = flag ? __bfloat162float(((const __hip_bfloat16*)boff)[col])
                                     : ((const float*)boff)[col];
            else           bj = flag ? __bfloat162float(((const __hip_bfloat16*)battn)[col - 256])
                                     : ((const float*)battn)[col - 256];
#pragma unroll
            for (int i = 0; i < 2; ++i)
#pragma unroll
                for (int r = 0; r < 4; ++r) {
                    const int rl = i * 16 + qd * 4 + r;
                    const float v = acc[i][j][r] + bj;
                    if (col < 256) Os[rl * 256 + col] = v;
                    else           Al[rl * 128 + col - 256] = (short)(pack_bf2(v, 0.f) & 0xffff);
                }
        }
        __syncthreads();
        const int rows_valid = min(32, ROWS - bm);
        const int4* srcO = (const int4*)smem;
        int4* dstO = (int4*)((char*)offsb + (size_t)p * 32768);
#pragma unroll
        for (int c = 0; c < 8; ++c) {
            const int idx = c * 256 + tid;
            if (idx < rows_valid * 64) dstO[idx] = srcO[idx];
        }
        const int4* srcA = (const int4*)(smem + 32768);
        int4* dstA = (int4*)((char*)awl + (size_t)p * 8192);
#pragma unroll
        for (int c = 0; c < 2; ++c) {
            const int idx = c * 256 + tid;
            if (idx < rows_valid * 16) dstA[idx] = srcA[idx];
        }
    }
}

// output GEMM: block owns 32-row panel x 256 cols; C dtype per flag.
__global__ __launch_bounds__(256) void wgemm_out_k(
    const void* __restrict__ tmp, const short* __restrict__ wt,
    const void* __restrict__ bout, void* __restrict__ dout,
    const int* __restrict__ flagp)
{
    __shared__ __align__(16) char smem[32768];
    const int flag = *flagp;
    const int p = xcd_swz(blockIdx.x, NGRID_OUT), bm = p * 32;
    const int tid = threadIdx.x, wv = tid >> 6, lane = tid & 63;
    const int qd = lane >> 4, ln = lane & 15;

    floatx4 acc[2][4];
    wg_compute<4>(tmp, wt + WT_WOUT, true, bm, wv * 64, lane, acc);

#pragma unroll
    for (int j = 0; j < 4; ++j) {
        const int col = wv * 64 + j * 16 + ln;
        const float bj = flag ? __bfloat162float(((const __hip_bfloat16*)bout)[col])
                              : ((const float*)bout)[col];
#pragma unroll
        for (int i = 0; i < 2; ++i)
#pragma unroll
            for (int r = 0; r < 4; ++r) {
                const int rl = i * 16 + qd * 4 + r;
                const float v = acc[i][j][r] + bj;
                if (flag) ((short*)smem)[rl * 256 + col] = (short)(pack_bf2(v, 0.f) & 0xffff);
                else      ((float*)smem)[rl * 256 + col] = v;
            }
    }
    __syncthreads();
    const int rows_valid = min(32, ROWS - bm);
    const int4* src = (const int4*)smem;
    if (flag) {
        int4* dst = (int4*)((char*)dout + (size_t)p * 16384);
#pragma unroll
        for (int c = 0; c < 4; ++c) {
            const int idx = c * 256 + tid;
            if (idx < rows_valid * 32) dst[idx] = src[idx];
        }
    } else {
        int4* dst = (int4*)((char*)dout + (size_t)p * 32768);
#pragma unroll
        for (int c = 0; c < 8; ++c) {
            const int idx = c * 256 + tid;
            if (idx < rows_valid * 64) dst[idx] = src[idx];
        }
    }
}

// ---------------------------------------------------------------------------
// Sampler (settled since R3): owner-computes records + chunked gather.
// L2-gather-THROUGHPUT-bound: dur flat 62-67us across ILP 2x..16x schedules.
// Lowest-VGPR (36) form kept. recs [16][9][5]: 0 bank conflicts measured.
__global__ __launch_bounds__(256) void sampler_k(
    const void* __restrict__ refp, const short* __restrict__ value,
    const float* __restrict__ offs, const short* __restrict__ awl,
    short* __restrict__ tmp, const int* __restrict__ flagp)
{
    const int flag = *flagp;
    const int wq = threadIdx.x >> 6;                    // wave in block (query slot)
    const int nq = blockIdx.x * 4 + wq;                 // ROWS = 4*6647 exact
    const int lane = threadIdx.x & 63;
    const int h = lane >> 3, u = lane & 7;
    const int n = (nq >= LQ) ? 1 : 0;

    __shared__ int2 recs[4][16][9][5];                  // 23040 B

    // ---- softmax over 16 logits/head; lane u holds idx 2u, 2u+1
    const int lg = *(const int*)(awl + nq * 128 + h * 16 + u * 2);
    float l0 = blo(lg), l1 = bhif(lg);
    float m = fmaxf(l0, l1);
    m = fmaxf(m, __shfl_xor(m, 1));
    m = fmaxf(m, __shfl_xor(m, 2));
    m = fmaxf(m, __shfl_xor(m, 4));
    float e0 = __expf(l0 - m), e1 = __expf(l1 - m);
    float s = e0 + e1;
    s += __shfl_xor(s, 1);
    s += __shfl_xor(s, 2);
    s += __shfl_xor(s, 4);
    const float inv = 1.f / s;
    const float w0 = e0 * inv, w1 = e1 * inv;

    // ---- offsets: lane u holds (ox,oy) of idx 2u (x,y) and 2u+1 (z,w)
    const float4 of = *(const float4*)(offs + nq * 256 + h * 32 + u * 4);

    // ---- refpoint: lane u holds level (u&3)
    float rxl, ryl;
    if (flag) {
        const int rr = *(const int*)((const short*)refp + nq * 8 + (u & 3) * 2);
        rxl = blo(rr); ryl = bhif(rr);
    } else {
        const float* rp = (const float*)refp + nq * 8 + (u & 3) * 2;
        rxl = rp[0]; ryl = rp[1];
    }

    // ---- phase 1: owner computes corner records for its 2 idx (level l=u>>1)
    const int l = u >> 1;
    const int Wl = (0x0D193264 >> (l * 8)) & 0xff;      // 100,50,25,13
    const int St = (l == 0) ? 0 : (l == 1) ? 10000 : (l == 2) ? 12500 : 13125;
    const int rowbase = n * LQ + St;
    const float Wf = (float)Wl;
    const float rx = __shfl(rxl, h * 8 + l);
    const float ry = __shfl(ryl, h * 8 + l);

#pragma unroll
    for (int j = 0; j < 2; ++j) {
        const float ox = j ? of.z : of.x;
        const float oy = j ? of.w : of.y;
        const float wa = j ? w1 : w0;
        const float px = fmaf(rx, Wf, ox) - 0.5f;
        const float py = fmaf(ry, Wf, oy) - 0.5f;       // H == W at every level
        const float x0f = floorf(px), y0f = floorf(py);
        const float wx = px - x0f, wy = py - y0f;
        const int x0 = (int)x0f, y0 = (int)y0f;
        const float wxc[2] = {1.f - wx, wx};
        const float wyc[2] = {1.f - wy, wy};
#pragma unroll
        for (int dy = 0; dy < 2; ++dy) {
#pragma unroll
            for (int dx = 0; dx < 2; ++dx) {
                const int xi = x0 + dx, yi = y0 + dy;
                const bool vld = ((unsigned)xi < (unsigned)Wl) & ((unsigned)yi < (unsigned)Wl);
                int row = rowbase + yi * Wl + xi;       // garbage ok if !vld
                row = vld ? row : rowbase;              // any in-bounds row; w=0
                recs[wq][u * 2 + j][h][dy * 2 + dx] =
                    make_int2(row << 9, __float_as_int(vld ? wa * wxc[dx] * wyc[dy] : 0.f));
            }
        }
    }

    __syncthreads();

    // ---- phase 2: chunked gather; lane owns dims d = u*4..u*4+3 of head h
    const int laneoff = h * 64 + u * 8;                 // bytes within 512-B row
    const char* vb = (const char*)value;
    float a0 = 0.f, a1 = 0.f, a2 = 0.f, a3 = 0.f;

    int2  rA[8], rB[8];
    float wA[8], wB[8];

#define CHUNK(RW, WW, kk)                                                 \
    _Pragma("unroll")                                                     \
    for (int j = 0; j < 8; ++j) {                                         \
        const int2 rr = recs[wq][(kk) * 2 + (j >> 2)][h][j & 3];          \
        WW[j] = __int_as_float(rr.y);                                     \
        RW[j] = *(const int2*)(vb + (unsigned)(rr.x + laneoff));          \
    }
#define EAT(RW, WW)                                                       \
    _Pragma("unroll")                                                     \
    for (int j = 0; j < 8; ++j) {                                         \
        a0 = fmaf(WW[j], blo(RW[j].x),  a0);                              \
        a1 = fmaf(WW[j], bhif(RW[j].x), a1);                              \
        a2 = fmaf(WW[j], blo(RW[j].y),  a2);                              \
        a3 = fmaf(WW[j], bhif(RW[j].y), a3);                              \
    }

    CHUNK(rA, wA, 0)
    CHUNK(rB, wB, 1)
    EAT(rA, wA)  CHUNK(rA, wA, 2)
    EAT(rB, wB)  CHUNK(rB, wB, 3)
    EAT(rA, wA)  CHUNK(rA, wA, 4)
    EAT(rB, wB)  CHUNK(rB, wB, 5)
    EAT(rA, wA)  CHUNK(rA, wA, 6)
    EAT(rB, wB)  CHUNK(rB, wB, 7)
    EAT(rA, wA)
    EAT(rB, wB)
#undef CHUNK
#undef EAT

    int2 o;
    o.x = pack_bf2(a0, a1);
    o.y = pack_bf2(a2, a3);
    *(int2*)(tmp + nq * 256 + h * 32 + u * 4) = o;
}

// ---------------------------------------------------------------------------
extern "C" void kernel_launch(void* const* d_in, const int* in_sizes, int n_in,
                              void* d_out, int out_size, void* d_ws, size_t ws_size,
                              hipStream_t stream)
{
    const void* query  = d_in[0];
    const void* refpts = d_in[1];
    const void* flat   = d_in[2];
    const void* Wv     = d_in[5];
    const void* bv     = d_in[6];
    const void* Woff   = d_in[7];
    const void* boff   = d_in[8];
    const void* Wattn  = d_in[9];
    const void* battn  = d_in[10];
    const void* Wout   = d_in[11];
    const void* bout   = d_in[12];

    char* ws = (char*)d_ws;
    short* value = (short*)(ws + OFF_VALUE);
    short* tmp   = (short*)(ws + OFF_TMP);
    float* offsb = (float*)(ws + OFF_OFFS);
    short* awl   = (short*)(ws + OFF_AWL);
    short* wt    = (short*)(ws + OFF_WT);
    int*   flagp = (int*)(ws + OFF_FLAG);

    sniff_k<<<1, 64, 0, stream>>>((const unsigned int*)query, flagp);
    trans_k<<<dim3(8, 8, 4), 256, 0, stream>>>(Wv, Woff, Wattn, Wout, wt, flagp);
    // merged: value = flat @ Wv + bv  |  offs/logits = q @ [Woff|Wattn] + b
    wgemm_in_k<<<NGRID_IN, 256, 0, stream>>>(flat, query, wt, bv, boff, battn,
                                             value, offsb, awl, flagp);
    sampler_k<<<ROWS / 4, 256, 0, stream>>>(refpts, value, offsb, awl, tmp, flagp);
    // out = tmp @ Wout + bout -> d_out (dtype per flag)
    wgemm_out_k<<<NGRID_OUT, 256, 0, stream>>>(tmp, wt, bout, d_out, flagp);
}